// Round 4
// baseline (218.208 us; speedup 1.0000x reference)
//
#include <hip/hip_runtime.h>

// ChannelAttention b=2, n=4096, c=32 fp32.
// S = X X^T (Gram), softmax over j per row i, out[j,c] = sum_i attn[i,j] x[i,c]; out*g + x.
//
// ROUND 4 = DIAGNOSTIC: identical kernels to R3, but the whole 3-kernel
// pipeline is launched 4x back-to-back (idempotent, same work every call).
// Purpose: dur_now = F + K (F = harness ws-poison fills possibly inside the
// measured span, K = our kernels). dur_x4 = F + 4K  =>  K = (dur_x4 - 94.7)/3.
// Disambiguates whether the 94.7 us is ~82 us of harness fill + ~13 us of
// kernels (my cycle model) or genuinely kernel-dominated.

typedef _Float16 half8 __attribute__((ext_vector_type(8)));
typedef _Float16 half4v __attribute__((ext_vector_type(4)));
typedef float float4v __attribute__((ext_vector_type(4)));

#define NN 4096
#define CC 32
#define L2E 1.44269504f
#define SHIFT 48.0f

// ---------------- k0: fp32 -> fp16 row-major + fp16 transposed ----------------
__global__ __launch_bounds__(256) void k_convert(const float* __restrict__ x,
                                                 _Float16* __restrict__ xf,
                                                 _Float16* __restrict__ xt) {
    const int t = blockIdx.x * 256 + threadIdx.x;   // 65536 threads
    const int n  = t & 4095;
    const int cg = (t >> 12) & 7;
    const int b  = t >> 15;
    const int row = (b << 12) | n;
    const float4* src = (const float4*)(x + (size_t)row * CC + cg * 4);
    float4 v = *src;
    _Float16 h0 = (_Float16)v.x, h1 = (_Float16)v.y, h2 = (_Float16)v.z, h3 = (_Float16)v.w;
    *(half4v*)(xf + (size_t)row * CC + cg * 4) = (half4v){h0, h1, h2, h3};
    _Float16* xtb = xt + (size_t)b * CC * NN;
    xtb[(cg * 4 + 0) * NN + n] = h0;   // consecutive lanes -> consecutive n: coalesced
    xtb[(cg * 4 + 1) * NN + n] = h1;
    xtb[(cg * 4 + 2) * NN + n] = h2;
    xtb[(cg * 4 + 3) * NN + n] = h3;
}

// ---------------- k1: per-row shifted sum-of-exp -> c2[i] ----------------
__global__ __launch_bounds__(512) void k_pass1(const _Float16* __restrict__ xf,
                                               float* __restrict__ c2out) {
    const int tid = threadIdx.x;
    const int wave = tid >> 6, lane = tid & 63;
    const int quad = lane >> 4, l15 = lane & 15;
    const int b = blockIdx.x >> 8;
    const int i0 = (blockIdx.x & 255) * 16;
    const _Float16* xb = xf + (size_t)b * NN * CC;

    const half8 afrag = *(const half8*)(xb + (size_t)(i0 + l15) * CC + quad * 8);
    const float4v zf = {0.f, 0.f, 0.f, 0.f};
    float z[4] = {0.f, 0.f, 0.f, 0.f};
    const float c2c = -SHIFT * L2E;

    const int jbase = wave * 512;
    for (int jt = 0; jt < 8; ++jt) {           // 8 iters x 4 tiles x 16 j = 512 j
        const int j0 = jbase + jt * 64;
        half8 b0 = *(const half8*)(xb + (size_t)(j0 + l15) * CC + quad * 8);
        half8 b1 = *(const half8*)(xb + (size_t)(j0 + 16 + l15) * CC + quad * 8);
        half8 b2 = *(const half8*)(xb + (size_t)(j0 + 32 + l15) * CC + quad * 8);
        half8 b3 = *(const half8*)(xb + (size_t)(j0 + 48 + l15) * CC + quad * 8);
        float4v s0 = __builtin_amdgcn_mfma_f32_16x16x32_f16(afrag, b0, zf, 0, 0, 0);
        float4v s1 = __builtin_amdgcn_mfma_f32_16x16x32_f16(afrag, b1, zf, 0, 0, 0);
        float4v s2 = __builtin_amdgcn_mfma_f32_16x16x32_f16(afrag, b2, zf, 0, 0, 0);
        float4v s3 = __builtin_amdgcn_mfma_f32_16x16x32_f16(afrag, b3, zf, 0, 0, 0);
#pragma unroll
        for (int r = 0; r < 4; ++r) {
            z[r] += __builtin_amdgcn_exp2f(fmaf(s0[r], L2E, c2c));
            z[r] += __builtin_amdgcn_exp2f(fmaf(s1[r], L2E, c2c));
            z[r] += __builtin_amdgcn_exp2f(fmaf(s2[r], L2E, c2c));
            z[r] += __builtin_amdgcn_exp2f(fmaf(s3[r], L2E, c2c));
        }
    }
#pragma unroll
    for (int off = 1; off <= 8; off <<= 1) {
#pragma unroll
        for (int r = 0; r < 4; ++r) z[r] += __shfl_xor(z[r], off, 64);
    }
    __shared__ float zw[8][16];
    if (l15 == 0) {
#pragma unroll
        for (int r = 0; r < 4; ++r) zw[wave][quad * 4 + r] = z[r];
    }
    __syncthreads();
    if (tid < 16) {
        float zs = 0.f;
#pragma unroll
        for (int w = 0; w < 8; ++w) zs += zw[w][tid];
        c2out[b * NN + i0 + tid] = -(__builtin_amdgcn_logf(zs) + SHIFT * L2E);
    }
}

// ---------------- k2: output pass ----------------
__global__ __launch_bounds__(512) void k_pass2(const _Float16* __restrict__ xf,
                                               const _Float16* __restrict__ xt,
                                               const float* __restrict__ c2,
                                               const float* __restrict__ x,
                                               const float* __restrict__ gamma,
                                               float* __restrict__ out) {
    const int tid = threadIdx.x;
    const int wave = tid >> 6, lane = tid & 63;
    const int quad = lane >> 4, l15 = lane & 15;
    const int b = blockIdx.x >> 8;
    const int j0 = (blockIdx.x & 255) * 16;
    const _Float16* xb  = xf + (size_t)b * NN * CC;
    const _Float16* xtb = xt + (size_t)b * CC * NN;
    const float* c2b = c2 + b * NN;

    __shared__ _Float16 pt[8][2][16 * 40];   // wave x parity x (16 rows, stride 40)
    __shared__ float red[8][16][32];

    const half8 bjfrag = *(const half8*)(xb + (size_t)(j0 + l15) * CC + quad * 8);
    const float4v zf = {0.f, 0.f, 0.f, 0.f};
    float4v acc0 = zf, acc1 = zf;

    const int ibase = wave * 512;
    half8 a0  = *(const half8*)(xb + (size_t)(ibase + l15) * CC + quad * 8);
    half8 a1  = *(const half8*)(xb + (size_t)(ibase + 16 + l15) * CC + quad * 8);
    half8 xb0 = *(const half8*)(xtb + (size_t)l15 * NN + ibase + quad * 8);
    half8 xb1 = *(const half8*)(xtb + (size_t)(l15 + 16) * NN + ibase + quad * 8);
    float4v c20 = *(const float4v*)(c2b + ibase + quad * 4);
    float4v c21 = *(const float4v*)(c2b + ibase + 16 + quad * 4);

    for (int it = 0; it < 16; ++it) {
        const int inx = ibase + ((it + 1) & 15) * 32;
        half8 na0  = *(const half8*)(xb + (size_t)(inx + l15) * CC + quad * 8);
        half8 na1  = *(const half8*)(xb + (size_t)(inx + 16 + l15) * CC + quad * 8);
        half8 nxb0 = *(const half8*)(xtb + (size_t)l15 * NN + inx + quad * 8);
        half8 nxb1 = *(const half8*)(xtb + (size_t)(l15 + 16) * NN + inx + quad * 8);
        float4v nc20 = *(const float4v*)(c2b + inx + quad * 4);
        float4v nc21 = *(const float4v*)(c2b + inx + 16 + quad * 4);

        float4v s0 = __builtin_amdgcn_mfma_f32_16x16x32_f16(a0, bjfrag, zf, 0, 0, 0);
        float4v s1 = __builtin_amdgcn_mfma_f32_16x16x32_f16(a1, bjfrag, zf, 0, 0, 0);
        half4v p0, p1;
#pragma unroll
        for (int r = 0; r < 4; ++r) {
            p0[r] = (_Float16)__builtin_amdgcn_exp2f(fmaf(s0[r], L2E, c20[r]));
            p1[r] = (_Float16)__builtin_amdgcn_exp2f(fmaf(s1[r], L2E, c21[r]));
        }
        _Float16* ptw = &pt[wave][it & 1][0];
        *(half4v*)(ptw + l15 * 40 + quad * 4)      = p0;
        *(half4v*)(ptw + l15 * 40 + 16 + quad * 4) = p1;
        half8 a2 = *(const half8*)(ptw + l15 * 40 + quad * 8);   // P^T[j=l15][i]
        acc0 = __builtin_amdgcn_mfma_f32_16x16x32_f16(a2, xb0, acc0, 0, 0, 0);
        acc1 = __builtin_amdgcn_mfma_f32_16x16x32_f16(a2, xb1, acc1, 0, 0, 0);

        a0 = na0; a1 = na1; xb0 = nxb0; xb1 = nxb1; c20 = nc20; c21 = nc21;
    }

#pragma unroll
    for (int r = 0; r < 4; ++r) {
        red[wave][quad * 4 + r][l15]      = acc0[r];
        red[wave][quad * 4 + r][l15 + 16] = acc1[r];
    }
    __syncthreads();
    {
        const int jj = tid >> 5, c = tid & 31;   // 512 threads = 16 j x 32 c
        float s = 0.f;
#pragma unroll
        for (int w = 0; w < 8; ++w) s += red[w][jj][c];
        const float g = gamma[0];
        const size_t o = (size_t)(b * NN + j0 + jj) * CC + c;
        out[o] = fmaf(g, s, x[o]);
    }
}

extern "C" void kernel_launch(void* const* d_in, const int* in_sizes, int n_in,
                              void* d_out, int out_size, void* d_ws, size_t ws_size,
                              hipStream_t stream) {
    const float* x     = (const float*)d_in[0];
    const float* gamma = (const float*)d_in[1];
    float* out = (float*)d_out;

    // ws layout: Xf16 (512 KB) | XT f16 (512 KB) | c2 fp32 (32 KB)
    _Float16* xf = (_Float16*)d_ws;
    _Float16* xt = xf + (size_t)2 * NN * CC;
    float*    c2 = (float*)(xt + (size_t)2 * CC * NN);

    // DIAGNOSTIC: run the identical pipeline 4x (idempotent; same work every
    // call; graph-capture safe). dur_x4 = F + 4K  ->  K = (dur_x4 - 94.7)/3.
#pragma unroll
    for (int rep = 0; rep < 4; ++rep) {
        k_convert<<<dim3(256), dim3(256), 0, stream>>>(x, xf, xt);
        k_pass1 <<<dim3(512), dim3(512), 0, stream>>>(xf, c2);
        k_pass2 <<<dim3(512), dim3(512), 0, stream>>>(xf, xt, c2, x, gamma, out);
    }
}